// Round 1
// baseline (240.093 us; speedup 1.0000x reference)
//
#include <hip/hip_runtime.h>

// Problem constants (from reference setup_inputs)
constexpr int B = 4, C = 96, H = 192, W = 320;
constexpr int HW4    = (H * W) / 4;   // 15360 float4s per (b,c) plane
constexpr int OUT_CH = 81;            // (2*4+1)^2

// One thread per 4 consecutive w positions. For each spatial float4:
//   dot  = sum_c f1*f2        (per lane-elem, fp32)
//   asum = sum_c |f1|
//   r    = (asum > 0.1) ? dot/C : 0
// then broadcast r to all 81 output channels.
__global__ __launch_bounds__(256) void spike_corr_kernel(
    const float4* __restrict__ f1,
    const float4* __restrict__ f2,
    float4* __restrict__ out)
{
    const int idx = blockIdx.x * blockDim.x + threadIdx.x;  // [0, B*HW4)
    const int b = idx / HW4;
    const int s = idx - b * HW4;

    const float4* __restrict__ p1 = f1 + (size_t)b * C * HW4 + s;
    const float4* __restrict__ p2 = f2 + (size_t)b * C * HW4 + s;

    float dx = 0.f, dy = 0.f, dz = 0.f, dw = 0.f;
    float ax = 0.f, ay = 0.f, az = 0.f, aw = 0.f;

#pragma unroll 8
    for (int c = 0; c < C; ++c) {
        const float4 a = p1[(size_t)c * HW4];
        const float4 v = p2[(size_t)c * HW4];
        dx = fmaf(a.x, v.x, dx);
        dy = fmaf(a.y, v.y, dy);
        dz = fmaf(a.z, v.z, dz);
        dw = fmaf(a.w, v.w, dw);
        ax += fabsf(a.x);
        ay += fabsf(a.y);
        az += fabsf(a.z);
        aw += fabsf(a.w);
    }

    const float inv_c = 1.0f / (float)C;
    float4 r;
    r.x = (ax > 0.1f) ? dx * inv_c : 0.0f;
    r.y = (ay > 0.1f) ? dy * inv_c : 0.0f;
    r.z = (az > 0.1f) ? dz * inv_c : 0.0f;
    r.w = (aw > 0.1f) ? dw * inv_c : 0.0f;

    float4* __restrict__ po = out + (size_t)b * OUT_CH * HW4 + s;
#pragma unroll 1
    for (int o = 0; o < OUT_CH; ++o) {
        po[(size_t)o * HW4] = r;
    }
}

extern "C" void kernel_launch(void* const* d_in, const int* in_sizes, int n_in,
                              void* d_out, int out_size, void* d_ws, size_t ws_size,
                              hipStream_t stream) {
    const float4* f1 = (const float4*)d_in[0];
    const float4* f2 = (const float4*)d_in[1];
    float4* out = (float4*)d_out;

    const int total_threads = B * HW4;              // 61440
    const int block = 256;
    const int grid = (total_threads + block - 1) / block;  // 240

    spike_corr_kernel<<<grid, block, 0, stream>>>(f1, f2, out);
}

// Round 2
// 227.863 us; speedup vs baseline: 1.0537x; 1.0537x over previous
//
#include <hip/hip_runtime.h>

// Problem constants (from reference setup_inputs)
constexpr int B = 4, C = 96, H = 192, W = 320;
constexpr int HW     = H * W;        // 61440 floats per (b,c) plane
constexpr int OUT_CH = 81;           // (2*4+1)^2

// One thread per scalar spatial position (b,h,w).
//   dot  = sum_c f1*f2   (fp32)
//   asum = sum_c |f1|
//   r    = (asum > 0.1) ? dot/C : 0
// broadcast r to all 81 output channels (nontemporal: output is write-once).
//
// Grid: 960 blocks x 256 threads = 245,760 threads -> ~3.75 blocks/CU,
// ~15 waves/CU. R1's float4 version had only 240 blocks (16 CUs idle,
// 4 waves/CU, 8.7% occupancy) and ran latency-bound at 22% of HBM peak.
__global__ __launch_bounds__(256) void spike_corr_kernel(
    const float* __restrict__ f1,
    const float* __restrict__ f2,
    float* __restrict__ out)
{
    const int idx = blockIdx.x * blockDim.x + threadIdx.x;  // [0, B*HW)
    const int b = idx / HW;
    const int s = idx - b * HW;

    const float* __restrict__ p1 = f1 + (size_t)b * C * HW + s;
    const float* __restrict__ p2 = f2 + (size_t)b * C * HW + s;

    float dot = 0.f;
    float asum = 0.f;

#pragma unroll 16
    for (int c = 0; c < C; ++c) {
        const float a = p1[(size_t)c * HW];
        const float v = p2[(size_t)c * HW];
        dot = fmaf(a, v, dot);
        asum += fabsf(a);
    }

    const float r = (asum > 0.1f) ? dot * (1.0f / (float)C) : 0.0f;

    float* __restrict__ po = out + (size_t)b * OUT_CH * HW + s;
#pragma unroll 1
    for (int o = 0; o < OUT_CH; ++o) {
        __builtin_nontemporal_store(r, po + (size_t)o * HW);
    }
}

extern "C" void kernel_launch(void* const* d_in, const int* in_sizes, int n_in,
                              void* d_out, int out_size, void* d_ws, size_t ws_size,
                              hipStream_t stream) {
    const float* f1 = (const float*)d_in[0];
    const float* f2 = (const float*)d_in[1];
    float* out = (float*)d_out;

    const int total_threads = B * HW;               // 245760
    const int block = 256;
    const int grid = total_threads / block;         // 960 (exact)

    spike_corr_kernel<<<grid, block, 0, stream>>>(f1, f2, out);
}

// Round 3
// 225.848 us; speedup vs baseline: 1.0631x; 1.0089x over previous
//
#include <hip/hip_runtime.h>

// Problem constants (from reference setup_inputs)
constexpr int B = 4, C = 96, H = 192, W = 320;
constexpr int HW      = H * W;       // 61440 floats per (b,c) plane
constexpr int HW4     = HW / 4;      // 15360 float4 per (b,c) plane
constexpr int OUT_CH  = 81;
constexpr int GROUPS  = 4;           // channel groups per block (phase 1)
constexpr int CPG     = C / GROUPS;  // 24 channels per group
constexpr int SPB     = 64;          // spatial float4 per block (phase 1)
constexpr int TOTAL_S4  = B * HW4;           // 61440 corr float4s
constexpr int TOTAL_OUT4 = B * OUT_CH * HW4; // 4,976,640 output float4s

typedef float f32x4 __attribute__((ext_vector_type(4)));

// ---------------- Phase 1: corr map (reads-dominated) ----------------
// Block = 256 threads = 64 spatial-float4 x 4 channel-groups.
// Each thread accumulates dot & |f1|-sum over its 24 channels (float4 lanes),
// LDS-reduces across the 4 groups, wave 0 writes the 983 KB corr map.
__global__ __launch_bounds__(256) void corr_phase1(
    const f32x4* __restrict__ f1,
    const f32x4* __restrict__ f2,
    f32x4* __restrict__ corr)
{
    __shared__ f32x4 sdot[GROUPS][SPB];
    __shared__ f32x4 sasum[GROUPS][SPB];

    const int s_local = threadIdx.x & 63;
    const int g       = threadIdx.x >> 6;
    const int base4   = blockIdx.x * SPB;        // global spatial-f4 index
    const int b       = base4 / HW4;             // SPB divides HW4: no straddle
    const int splane  = (base4 - b * HW4) + s_local;

    const f32x4* __restrict__ p1 = f1 + ((size_t)(b * C + g * CPG)) * HW4 + splane;
    const f32x4* __restrict__ p2 = f2 + ((size_t)(b * C + g * CPG)) * HW4 + splane;

    f32x4 d = {0.f, 0.f, 0.f, 0.f};
    f32x4 a = {0.f, 0.f, 0.f, 0.f};

#pragma unroll 8
    for (int j = 0; j < CPG; ++j) {
        const f32x4 x = p1[(size_t)j * HW4];
        const f32x4 y = p2[(size_t)j * HW4];
        d.x = fmaf(x.x, y.x, d.x);
        d.y = fmaf(x.y, y.y, d.y);
        d.z = fmaf(x.z, y.z, d.z);
        d.w = fmaf(x.w, y.w, d.w);
        a.x += fabsf(x.x);
        a.y += fabsf(x.y);
        a.z += fabsf(x.z);
        a.w += fabsf(x.w);
    }

    sdot[g][s_local]  = d;
    sasum[g][s_local] = a;
    __syncthreads();

    if (g == 0) {
        f32x4 dt = sdot[0][s_local];
        f32x4 at = sasum[0][s_local];
#pragma unroll
        for (int k = 1; k < GROUPS; ++k) {
            const f32x4 dk = sdot[k][s_local];
            const f32x4 ak = sasum[k][s_local];
            dt.x += dk.x; dt.y += dk.y; dt.z += dk.z; dt.w += dk.w;
            at.x += ak.x; at.y += ak.y; at.z += ak.z; at.w += ak.w;
        }
        const float inv_c = 1.0f / (float)C;
        f32x4 r;
        r.x = (at.x > 0.1f) ? dt.x * inv_c : 0.0f;
        r.y = (at.y > 0.1f) ? dt.y * inv_c : 0.0f;
        r.z = (at.z > 0.1f) ? dt.z * inv_c : 0.0f;
        r.w = (at.w > 0.1f) ? dt.w * inv_c : 0.0f;
        corr[base4 + s_local] = r;   // regular store: stays cached for phase 2
    }
}

// ---------------- Phase 2: broadcast (writes-dominated) ----------------
// One thread per output float4; consecutive threads/blocks walk the 78 MB
// output LINEARLY. corr (983 KB) hits L2/L3. NT stores keep output out of L3.
__global__ __launch_bounds__(256) void corr_phase2(
    const f32x4* __restrict__ corr,
    f32x4* __restrict__ out)
{
    const int idx   = blockIdx.x * 256 + threadIdx.x;   // [0, TOTAL_OUT4)
    const int plane = idx / HW4;                        // = b*81 + o
    const int s4    = idx - plane * HW4;
    const int b     = plane / OUT_CH;
    const f32x4 r = corr[(size_t)b * HW4 + s4];
    __builtin_nontemporal_store(r, out + idx);
}

// ---------------- Fallback (ws too small): R2 single kernel ----------------
__global__ __launch_bounds__(256) void spike_corr_mono(
    const float* __restrict__ f1,
    const float* __restrict__ f2,
    float* __restrict__ out)
{
    const int idx = blockIdx.x * blockDim.x + threadIdx.x;
    const int b = idx / HW;
    const int s = idx - b * HW;
    const float* __restrict__ p1 = f1 + (size_t)b * C * HW + s;
    const float* __restrict__ p2 = f2 + (size_t)b * C * HW + s;
    float dot = 0.f, asum = 0.f;
#pragma unroll 16
    for (int c = 0; c < C; ++c) {
        const float a = p1[(size_t)c * HW];
        const float v = p2[(size_t)c * HW];
        dot = fmaf(a, v, dot);
        asum += fabsf(a);
    }
    const float r = (asum > 0.1f) ? dot * (1.0f / (float)C) : 0.0f;
    float* __restrict__ po = out + (size_t)b * OUT_CH * HW + s;
#pragma unroll 1
    for (int o = 0; o < OUT_CH; ++o)
        __builtin_nontemporal_store(r, po + (size_t)o * HW);
}

extern "C" void kernel_launch(void* const* d_in, const int* in_sizes, int n_in,
                              void* d_out, int out_size, void* d_ws, size_t ws_size,
                              hipStream_t stream) {
    const size_t corr_bytes = (size_t)TOTAL_S4 * sizeof(f32x4);  // 983,040 B

    if (ws_size >= corr_bytes) {
        const f32x4* f1 = (const f32x4*)d_in[0];
        const f32x4* f2 = (const f32x4*)d_in[1];
        f32x4* corr = (f32x4*)d_ws;
        f32x4* out  = (f32x4*)d_out;

        corr_phase1<<<TOTAL_S4 / SPB, 256, 0, stream>>>(f1, f2, corr);   // 960 blocks
        corr_phase2<<<TOTAL_OUT4 / 256, 256, 0, stream>>>(corr, out);    // 19440 blocks
    } else {
        const float* f1 = (const float*)d_in[0];
        const float* f2 = (const float*)d_in[1];
        float* out = (float*)d_out;
        spike_corr_mono<<<(B * HW) / 256, 256, 0, stream>>>(f1, f2, out);
    }
}